// Round 1
// baseline (151.491 us; speedup 1.0000x reference)
//
#include <hip/hip_runtime.h>
#include <cstddef>

// Problem constants (match reference)
#define SB  2
#define SS  4096
#define SH  8
#define SD  64
#define SP  64      // W/2 = pad = half-window
#define SNO 129     // W+1 offsets
#define TQ  32      // query tokens per block
#define YS  160     // TQ + 2*SP key positions per block
#define NROWS (SB*SS*SH)  // 65536 projection rows

__device__ __forceinline__ float fast_tanh(float x) {
  // tanh(x) = sign(x) * (1 - 2/(e^{2|x|}+1)); safe for large |x| (exp->inf -> 1)
  float ax = fabsf(x);
  float e = __expf(2.0f * ax);
  float t = 1.0f - 2.0f / (e + 1.0f);
  return copysignf(t, x);
}

// XP[row][d] = sum_e X[row][e] * Wm[d][e] + bias[d]; 64 rows per block.
__global__ __launch_bounds__(256) void proj_kernel(
    const float* __restrict__ X, const float* __restrict__ Wm,
    const float* __restrict__ bias, float* __restrict__ XP)
{
  __shared__ float Ws[64][68];   // Ws[e][d] = Wm[d][e]
  __shared__ float Xs[64][68];   // Xs[e][r]
  __shared__ float bs[64];

  int t = threadIdx.x;
  size_t row0 = (size_t)blockIdx.x * 64;
  int sub = t >> 4;            // 0..15
  int e4  = (t & 15) * 4;

  #pragma unroll
  for (int p = 0; p < 4; ++p) {
    int d = p * 16 + sub;      // 0..63 (doubles as row index for X staging)
    float4 w = *(const float4*)(Wm + d * 64 + e4);
    Ws[e4+0][d] = w.x; Ws[e4+1][d] = w.y; Ws[e4+2][d] = w.z; Ws[e4+3][d] = w.w;
    float4 x = *(const float4*)(X + (row0 + d) * 64 + e4);
    Xs[e4+0][d] = x.x; Xs[e4+1][d] = x.y; Xs[e4+2][d] = x.z; Xs[e4+3][d] = x.w;
  }
  if (t < 64) bs[t] = bias[t];
  __syncthreads();

  int rl = (t >> 4) * 4;   // 4 rows
  int dl = (t & 15) * 4;   // 4 cols
  float acc[4][4];
  #pragma unroll
  for (int r = 0; r < 4; ++r)
    #pragma unroll
    for (int c = 0; c < 4; ++c) acc[r][c] = bs[dl + c];

  #pragma unroll 8
  for (int e = 0; e < 64; ++e) {
    float4 xv = *(float4*)&Xs[e][rl];
    float4 wv = *(float4*)&Ws[e][dl];
    float xr[4] = {xv.x, xv.y, xv.z, xv.w};
    float wc[4] = {wv.x, wv.y, wv.z, wv.w};
    #pragma unroll
    for (int r = 0; r < 4; ++r)
      #pragma unroll
      for (int c = 0; c < 4; ++c)
        acc[r][c] = fmaf(xr[r], wc[c], acc[r][c]);
  }

  #pragma unroll
  for (int r = 0; r < 4; ++r) {
    float4 o4 = make_float4(acc[r][0], acc[r][1], acc[r][2], acc[r][3]);
    *(float4*)(XP + (row0 + rl + r) * 64 + dl) = o4;
  }
}

// One block per (batch, 32-query tile). Loops over 8 heads.
// Phases per head: stage -> scores(tanh)->Ss -> attn_flat writes + PV partials -> reduce.
__global__ __launch_bounds__(512) void attn_kernel(
    const float* __restrict__ qp, const float* __restrict__ kp,
    const float* __restrict__ v, const float* __restrict__ ocpe,
    float* __restrict__ af, float* __restrict__ op)
{
  __shared__ float Qs[TQ][68];
  __shared__ float Ks[YS][68];
  __shared__ float Vt[64][172];   // Vt[d][y] (transposed for y-vectorized PV)
  __shared__ float Ss[TQ][YS];    // attn (post-tanh, masked)
  __shared__ float ob[SNO];

  int t = threadIdx.x;
  int b  = blockIdx.x / (SS / TQ);
  int t0 = (blockIdx.x % (SS / TQ)) * TQ;

  // Per-thread ownership for the out accumulator: i = t>>4, d = (t&15)*4 + k
  int ri = t >> 4;
  int rd = (t & 15) * 4;
  float accO[4] = {0.f, 0.f, 0.f, 0.f};

  // PV partial buffer aliases Ks (Ks is dead after the scores phase)
  float (*Pp)[TQ][68] = (float (*)[TQ][68])(&Ks[0][0]);

  for (int h = 0; h < SH; ++h) {
    __syncthreads();  // protect Qs/Ks(=Pp)/Vt from previous iteration readers

    if (t < SNO) ob[t] = ocpe[t * SH + h];
    // stage Q tile: 32x64, one float4 per thread
    {
      int i  = t >> 4;
      int e4 = (t & 15) * 4;
      *(float4*)&Qs[i][e4] =
          *(const float4*)(qp + (((size_t)b * SS + t0 + i) * SH + h) * SD + e4);
    }
    // stage K and V (transposed): 160x64 each, zero outside valid range
    #pragma unroll
    for (int rr = 0; rr < 5; ++rr) {
      int idx = t + 512 * rr;       // 0..2559
      int y   = idx >> 4;
      int e4  = (idx & 15) * 4;
      int yg  = t0 - SP + y;
      float4 kv = make_float4(0.f, 0.f, 0.f, 0.f);
      float4 vv = make_float4(0.f, 0.f, 0.f, 0.f);
      if (yg >= 0 && yg < SS) {
        size_t base = (((size_t)b * SS + yg) * SH + h) * SD + e4;
        kv = *(const float4*)(kp + base);
        vv = *(const float4*)(v + base);
      }
      *(float4*)&Ks[y][e4] = kv;
      Vt[e4+0][y] = vv.x; Vt[e4+1][y] = vv.y; Vt[e4+2][y] = vv.z; Vt[e4+3][y] = vv.w;
    }
    __syncthreads();

    // scores: 320 lanes, each a 4(i) x 4(y, stride-40) tile
    if (t < 320) {
      int tig = t / 40;
      int tyg = t - tig * 40;
      int i0  = tig * 4;
      float acc[4][4] = {};
      #pragma unroll 4
      for (int e = 0; e < SD; e += 4) {
        float4 qv[4], kv[4];
        #pragma unroll
        for (int r2 = 0; r2 < 4; ++r2) qv[r2] = *(float4*)&Qs[i0 + r2][e];
        #pragma unroll
        for (int c2 = 0; c2 < 4; ++c2) kv[c2] = *(float4*)&Ks[tyg + 40 * c2][e];
        #pragma unroll
        for (int r2 = 0; r2 < 4; ++r2)
          #pragma unroll
          for (int c2 = 0; c2 < 4; ++c2) {
            acc[r2][c2] = fmaf(qv[r2].x, kv[c2].x, acc[r2][c2]);
            acc[r2][c2] = fmaf(qv[r2].y, kv[c2].y, acc[r2][c2]);
            acc[r2][c2] = fmaf(qv[r2].z, kv[c2].z, acc[r2][c2]);
            acc[r2][c2] = fmaf(qv[r2].w, kv[c2].w, acc[r2][c2]);
          }
      }
      #pragma unroll
      for (int r2 = 0; r2 < 4; ++r2)
        #pragma unroll
        for (int c2 = 0; c2 < 4; ++c2) {
          int i = i0 + r2;
          int y = tyg + 40 * c2;
          int o = y - i;              // offset index into ocpe
          int yg = t0 - SP + y;
          float a = 0.f;
          if (o >= 0 && o <= 2 * SP && yg >= 0 && yg < SS)
            a = fast_tanh(acc[r2][c2] + ob[o]);
          Ss[i][y] = a;
        }
    }
    __syncthreads();

    // attn_flat writes (from Ss; masked entries already 0)
    {
      size_t abase = (((size_t)b * SS + t0) * SNO) * SH + h;
      for (int idx = t; idx < TQ * SNO; idx += 512) {
        int i = idx / SNO;
        int o = idx - i * SNO;
        af[abase + ((size_t)i * SNO + o) * SH] = Ss[i][i + o];
      }
    }
    // PV partials: 4 y-segments x (8 i-groups x 16 d-lanes); d columns stride-16
    {
      int seg  = t >> 7;          // 0..3 -> y in [seg*40, seg*40+40)
      int t2   = t & 127;
      int i0   = (t2 >> 4) * 4;
      int dsel = t2 & 15;
      float pacc[4][4] = {};
      int ybase = seg * 40;
      #pragma unroll 2
      for (int yq = 0; yq < 10; ++yq) {
        int y = ybase + yq * 4;
        float4 sv[4], vv[4];
        #pragma unroll
        for (int r2 = 0; r2 < 4; ++r2) sv[r2] = *(float4*)&Ss[i0 + r2][y];
        #pragma unroll
        for (int c2 = 0; c2 < 4; ++c2) vv[c2] = *(float4*)&Vt[dsel + 16 * c2][y];
        #pragma unroll
        for (int r2 = 0; r2 < 4; ++r2)
          #pragma unroll
          for (int c2 = 0; c2 < 4; ++c2) {
            pacc[r2][c2] = fmaf(sv[r2].x, vv[c2].x, pacc[r2][c2]);
            pacc[r2][c2] = fmaf(sv[r2].y, vv[c2].y, pacc[r2][c2]);
            pacc[r2][c2] = fmaf(sv[r2].z, vv[c2].z, pacc[r2][c2]);
            pacc[r2][c2] = fmaf(sv[r2].w, vv[c2].w, pacc[r2][c2]);
          }
      }
      #pragma unroll
      for (int r2 = 0; r2 < 4; ++r2)
        #pragma unroll
        for (int c2 = 0; c2 < 4; ++c2)
          Pp[seg][i0 + r2][dsel + 16 * c2] = pacc[r2][c2];
    }
    __syncthreads();
    // reduce 4 segments into persistent accO
    #pragma unroll
    for (int sgi = 0; sgi < 4; ++sgi) {
      float4 p = *(float4*)&Pp[sgi][ri][rd];
      accO[0] += p.x; accO[1] += p.y; accO[2] += p.z; accO[3] += p.w;
    }
  }

  {
    float4 o4 = make_float4(accO[0], accO[1], accO[2], accO[3]);
    *(float4*)(op + (((size_t)b * SS + t0 + ri) * SD) + rd) = o4;
  }
}

extern "C" void kernel_launch(void* const* d_in, const int* in_sizes, int n_in,
                              void* d_out, int out_size, void* d_ws, size_t ws_size,
                              hipStream_t stream) {
  const float* q    = (const float*)d_in[0];
  const float* k    = (const float*)d_in[1];
  const float* v    = (const float*)d_in[2];
  const float* Wq   = (const float*)d_in[3];
  const float* bq   = (const float*)d_in[4];
  const float* Wk   = (const float*)d_in[5];
  const float* bk   = (const float*)d_in[6];
  const float* ocpe = (const float*)d_in[7];

  // workspace: projected q and k, 16 MB each (requires ws_size >= 32 MB)
  float* qp  = (float*)d_ws;
  float* kp2 = qp + (size_t)NROWS * SD;

  float* af = (float*)d_out;                               // attn_flat
  float* op = af + (size_t)SB * SS * SNO * SH;             // out

  proj_kernel<<<NROWS / 64, 256, 0, stream>>>(q, Wq, bq, qp);
  proj_kernel<<<NROWS / 64, 256, 0, stream>>>(k, Wk, bk, kp2);
  attn_kernel<<<SB * (SS / TQ), 512, 0, stream>>>(qp, kp2, v, ocpe, af, op);
}

// Round 2
// 94.525 us; speedup vs baseline: 1.6027x; 1.6027x over previous
//
#include <hip/hip_runtime.h>
#include <cstddef>

#define SB  2
#define SS  4096
#define SH  8
#define SD  64
#define SP  64      // half-window
#define SNO 129     // W+1 offsets
#define TQ  32      // query tokens per block
#define YS  160     // TQ + 2*SP
#define NROWS (SB*SS*SH)
#define NTILES (SS/TQ)   // 128
#define PSTR 68     // padded bf16 stride for 64-wide rows
#define SSTR 168    // padded bf16 stride for Ss rows (160-wide)

typedef __attribute__((ext_vector_type(8))) __bf16 bf16x8;
typedef __attribute__((ext_vector_type(4))) float floatx4;

union frag_u { unsigned short us[8]; ushort4 u4[2]; bf16x8 v; };

__device__ __forceinline__ unsigned short f2bf(float x) {
  union { float f; unsigned u; } v; v.f = x;
  unsigned r = v.u + 0x7FFF + ((v.u >> 16) & 1);
  return (unsigned short)(r >> 16);
}
__device__ __forceinline__ float bf2f(unsigned short h) {
  union { float f; unsigned u; } v; v.u = ((unsigned)h) << 16;
  return v.f;
}
__device__ __forceinline__ void split_bf(float x, unsigned short& hi, unsigned short& lo) {
  hi = f2bf(x);
  lo = f2bf(x - bf2f(hi));
}

__device__ __forceinline__ float fast_tanh(float x) {
  float ax = fabsf(x);
  float e = __expf(2.0f * ax);
  float t = 1.0f - 2.0f / (e + 1.0f);
  return copysignf(t, x);
}

__device__ __forceinline__ bf16x8 ld_frag(const unsigned short* p) {
  frag_u f;
  f.u4[0] = *(const ushort4*)p;
  f.u4[1] = *(const ushort4*)(p + 4);
  return f.v;
}

// ---------------- K projection (f32, unchanged from round 1) ----------------
__global__ __launch_bounds__(256) void proj_kernel(
    const float* __restrict__ X, const float* __restrict__ Wm,
    const float* __restrict__ bias, float* __restrict__ XP)
{
  __shared__ float Ws[64][68];
  __shared__ float Xs[64][68];
  __shared__ float bs[64];

  int t = threadIdx.x;
  size_t row0 = (size_t)blockIdx.x * 64;
  int sub = t >> 4;
  int e4  = (t & 15) * 4;

  #pragma unroll
  for (int p = 0; p < 4; ++p) {
    int d = p * 16 + sub;
    float4 w = *(const float4*)(Wm + d * 64 + e4);
    Ws[e4+0][d] = w.x; Ws[e4+1][d] = w.y; Ws[e4+2][d] = w.z; Ws[e4+3][d] = w.w;
    float4 x = *(const float4*)(X + (row0 + d) * 64 + e4);
    Xs[e4+0][d] = x.x; Xs[e4+1][d] = x.y; Xs[e4+2][d] = x.z; Xs[e4+3][d] = x.w;
  }
  if (t < 64) bs[t] = bias[t];
  __syncthreads();

  int rl = (t >> 4) * 4;
  int dl = (t & 15) * 4;
  float acc[4][4];
  #pragma unroll
  for (int r = 0; r < 4; ++r)
    #pragma unroll
    for (int c = 0; c < 4; ++c) acc[r][c] = bs[dl + c];

  #pragma unroll 8
  for (int e = 0; e < 64; ++e) {
    float4 xv = *(float4*)&Xs[e][rl];
    float4 wv = *(float4*)&Ws[e][dl];
    float xr[4] = {xv.x, xv.y, xv.z, xv.w};
    float wc[4] = {wv.x, wv.y, wv.z, wv.w};
    #pragma unroll
    for (int r = 0; r < 4; ++r)
      #pragma unroll
      for (int c = 0; c < 4; ++c)
        acc[r][c] = fmaf(xr[r], wc[c], acc[r][c]);
  }

  #pragma unroll
  for (int r = 0; r < 4; ++r) {
    float4 o4 = make_float4(acc[r][0], acc[r][1], acc[r][2], acc[r][3]);
    *(float4*)(XP + (row0 + rl + r) * 64 + dl) = o4;
  }
}

// ---------------- fused attention (MFMA) ----------------
// One block per (batch, 32-query tile); loops over 8 heads.
template<bool AFWS>
__global__ __launch_bounds__(512, 4) void attn_mfma(
    const float* __restrict__ qraw, const float* __restrict__ kp,
    const float* __restrict__ v,    const float* __restrict__ ocpe,
    const float* __restrict__ Wq,   const float* __restrict__ bq,
    unsigned short* __restrict__ afws,
    float* __restrict__ af, float* __restrict__ op)
{
  __shared__ unsigned short sWh[64*PSTR], sWl[64*PSTR];   // Wq hi/lo, rows d, cols e
  __shared__ unsigned short sKh[YS*PSTR], sKl[YS*PSTR];   // K hi/lo (V aliases sKh later)
  __shared__ unsigned short sQh[TQ*PSTR], sQl[TQ*PSTR];   // projected Q hi/lo
  __shared__ unsigned short sSs[TQ*SSTR];                 // attn bf16; qraw hi/lo alias here
  __shared__ float sOb[SNO];
  __shared__ float sBq[64];

  unsigned short* qrh = sSs;                 // 32*68 = 2176 u16
  unsigned short* qrl = sSs + TQ*PSTR;       // next 2176 (total 4352 <= 5376)

  int t = threadIdx.x;
  int lane = t & 63, wave = t >> 6;
  int b = blockIdx.x / NTILES;
  int tile = blockIdx.x - b * NTILES;
  int t0 = tile * TQ;

  // stage Wq hi/lo + bq once
  {
    int d = t >> 3, e8 = (t & 7) * 8;
    float4 w0 = *(const float4*)(Wq + d * 64 + e8);
    float4 w1 = *(const float4*)(Wq + d * 64 + e8 + 4);
    float wv[8] = {w0.x,w0.y,w0.z,w0.w,w1.x,w1.y,w1.z,w1.w};
    ushort4 hv0, hv1, lv0, lv1;
    unsigned short hh[8], ll[8];
    #pragma unroll
    for (int j = 0; j < 8; ++j) split_bf(wv[j], hh[j], ll[j]);
    hv0 = make_ushort4(hh[0],hh[1],hh[2],hh[3]); hv1 = make_ushort4(hh[4],hh[5],hh[6],hh[7]);
    lv0 = make_ushort4(ll[0],ll[1],ll[2],ll[3]); lv1 = make_ushort4(ll[4],ll[5],ll[6],ll[7]);
    *(ushort4*)&sWh[d*PSTR + e8]     = hv0;
    *(ushort4*)&sWh[d*PSTR + e8 + 4] = hv1;
    *(ushort4*)&sWl[d*PSTR + e8]     = lv0;
    *(ushort4*)&sWl[d*PSTR + e8 + 4] = lv1;
    if (t < 64) sBq[t] = bq[t];
  }

  floatx4 accPV = {0.f, 0.f, 0.f, 0.f};
  int r16 = lane & 15, g = lane >> 4;

  for (int h = 0; h < SH; ++h) {
    __syncthreads();   // prev-head readers done (also covers W staging on h==0)

    // (A) stage ob, qraw(hi/lo), K(hi/lo)
    if (t < SNO) sOb[t] = ocpe[t * SH + h];
    {
      int i = t >> 4, c4 = (t & 15) * 4;
      float4 qv = *(const float4*)(qraw + (((size_t)b*SS + t0 + i)*SH + h)*SD + c4);
      float x[4] = {qv.x,qv.y,qv.z,qv.w};
      unsigned short hh[4], ll[4];
      #pragma unroll
      for (int j = 0; j < 4; ++j) split_bf(x[j], hh[j], ll[j]);
      *(ushort4*)&qrh[i*PSTR + c4] = make_ushort4(hh[0],hh[1],hh[2],hh[3]);
      *(ushort4*)&qrl[i*PSTR + c4] = make_ushort4(ll[0],ll[1],ll[2],ll[3]);
    }
    #pragma unroll
    for (int rr = 0; rr < 5; ++rr) {
      int idx = t + 512 * rr;
      int y = idx >> 4, c4 = (idx & 15) * 4;
      int yg = t0 - SP + y;
      float4 kv = make_float4(0.f,0.f,0.f,0.f);
      if (yg >= 0 && yg < SS)
        kv = *(const float4*)(kp + (((size_t)b*SS + yg)*SH + h)*SD + c4);
      float x[4] = {kv.x,kv.y,kv.z,kv.w};
      unsigned short hh[4], ll[4];
      #pragma unroll
      for (int j = 0; j < 4; ++j) split_bf(x[j], hh[j], ll[j]);
      *(ushort4*)&sKh[y*PSTR + c4] = make_ushort4(hh[0],hh[1],hh[2],hh[3]);
      *(ushort4*)&sKl[y*PSTR + c4] = make_ushort4(ll[0],ll[1],ll[2],ll[3]);
    }
    __syncthreads();

    // (B) Q projection via MFMA: wave -> (i-tile, d-tile)
    {
      int i0 = (wave >> 2) * 16, d0 = (wave & 3) * 16;
      floatx4 acc = {0.f,0.f,0.f,0.f};
      #pragma unroll
      for (int e0 = 0; e0 < 64; e0 += 32) {
        int ec = e0 + g * 8;
        bf16x8 ah = ld_frag(&qrh[(i0 + r16)*PSTR + ec]);
        bf16x8 al = ld_frag(&qrl[(i0 + r16)*PSTR + ec]);
        bf16x8 bh = ld_frag(&sWh[(d0 + r16)*PSTR + ec]);
        bf16x8 bl = ld_frag(&sWl[(d0 + r16)*PSTR + ec]);
        acc = __builtin_amdgcn_mfma_f32_16x16x32_bf16(ah, bh, acc, 0, 0, 0);
        acc = __builtin_amdgcn_mfma_f32_16x16x32_bf16(ah, bl, acc, 0, 0, 0);
        acc = __builtin_amdgcn_mfma_f32_16x16x32_bf16(al, bh, acc, 0, 0, 0);
      }
      float bias = sBq[d0 + r16];
      #pragma unroll
      for (int r = 0; r < 4; ++r) {
        unsigned short hh, ll;
        split_bf(acc[r] + bias, hh, ll);
        sQh[(i0 + g*4 + r)*PSTR + d0 + r16] = hh;
        sQl[(i0 + g*4 + r)*PSTR + d0 + r16] = ll;
      }
    }
    __syncthreads();

    // (C) scores + bias + mask + tanh -> Ss (bf16)
    for (int ct = wave; ct < 20; ct += 8) {
      int ii = (ct >= 10) ? 1 : 0;
      int yy = ct - 10 * ii;
      int i0 = ii * 16, y0 = yy * 16;
      floatx4 acc = {0.f,0.f,0.f,0.f};
      #pragma unroll
      for (int e0 = 0; e0 < 64; e0 += 32) {
        int ec = e0 + g * 8;
        bf16x8 ah = ld_frag(&sQh[(i0 + r16)*PSTR + ec]);
        bf16x8 al = ld_frag(&sQl[(i0 + r16)*PSTR + ec]);
        bf16x8 bh = ld_frag(&sKh[(y0 + r16)*PSTR + ec]);
        bf16x8 bl = ld_frag(&sKl[(y0 + r16)*PSTR + ec]);
        acc = __builtin_amdgcn_mfma_f32_16x16x32_bf16(ah, bh, acc, 0, 0, 0);
        acc = __builtin_amdgcn_mfma_f32_16x16x32_bf16(ah, bl, acc, 0, 0, 0);
        acc = __builtin_amdgcn_mfma_f32_16x16x32_bf16(al, bh, acc, 0, 0, 0);
      }
      int y = y0 + r16;
      int yg = t0 - SP + y;
      bool yok = (yg >= 0) && (yg < SS);
      #pragma unroll
      for (int r = 0; r < 4; ++r) {
        int i = i0 + g*4 + r;
        int o = y - i;
        float a = 0.f;
        if (yok && o >= 0 && o <= 2*SP) a = fast_tanh(acc[r] + sOb[o]);
        sSs[i*SSTR + y] = f2bf(a);
      }
    }
    __syncthreads();

    // (D) stage V (bf16, natural layout) into sKh region; emit attn_flat
    #pragma unroll
    for (int rr = 0; rr < 5; ++rr) {
      int idx = t + 512 * rr;
      int y = idx >> 4, c4 = (idx & 15) * 4;
      int yg = t0 - SP + y;
      float4 vv = make_float4(0.f,0.f,0.f,0.f);
      if (yg >= 0 && yg < SS)
        vv = *(const float4*)(v + (((size_t)b*SS + yg)*SH + h)*SD + c4);
      *(ushort4*)&sKh[y*PSTR + c4] =
          make_ushort4(f2bf(vv.x), f2bf(vv.y), f2bf(vv.z), f2bf(vv.w));
    }
    {
      int i = t >> 4, l16 = t & 15;
      if (AFWS) {
        size_t base = ((size_t)(b*NTILES + tile)*SH + h)*(size_t)(TQ*SNO) + (size_t)i*SNO;
        #pragma unroll
        for (int r = 0; r < 9; ++r) {
          int o = l16 + 16 * r;
          if (o < SNO) afws[base + o] = sSs[i*SSTR + i + o];
        }
      } else {
        size_t abase = (((size_t)b*SS + t0 + i)*SNO)*SH + h;
        #pragma unroll
        for (int r = 0; r < 9; ++r) {
          int o = l16 + 16 * r;
          if (o < SNO) af[abase + (size_t)o*SH] = bf2f(sSs[i*SSTR + i + o]);
        }
      }
    }
    __syncthreads();

    // (E) PV: wave -> (i-tile, d-tile); accumulate across heads
    {
      int i0 = (wave >> 2) * 16, d0 = (wave & 3) * 16;
      #pragma unroll
      for (int ks = 0; ks < 5; ++ks) {
        int y0 = ks * 32;
        bf16x8 a = ld_frag(&sSs[(i0 + r16)*SSTR + y0 + g*8]);
        frag_u bv;
        int yb = y0 + g * 8;
        #pragma unroll
        for (int j = 0; j < 8; ++j)
          bv.us[j] = sKh[(yb + j)*PSTR + d0 + r16];
        accPV = __builtin_amdgcn_mfma_f32_16x16x32_bf16(a, bv.v, accPV, 0, 0, 0);
      }
    }
  }

  // write out
  {
    int i0 = (wave >> 2) * 16, d0 = (wave & 3) * 16;
    #pragma unroll
    for (int r = 0; r < 4; ++r)
      op[((size_t)b*SS + t0 + i0 + g*4 + r)*SD + d0 + r16] = accPV[r];
  }
}

// ---------------- af transpose: ws bf16 [b,tile,h,i,o] -> out f32 [b,s,o,h] ----
__global__ __launch_bounds__(512) void af_transpose(
    const unsigned short* __restrict__ afws, float* __restrict__ af)
{
  int t = threadIdx.x;
  int b = blockIdx.x / NTILES;
  int tile = blockIdx.x - b * NTILES;
  int t0 = tile * TQ;
  int i = t >> 4, l16 = t & 15;
  size_t sbase = ((size_t)(b*NTILES + tile)*SH)*(size_t)(TQ*SNO) + (size_t)i*SNO;
  size_t obase = (((size_t)b*SS + t0 + i)*SNO)*SH;
  #pragma unroll
  for (int r = 0; r < 9; ++r) {
    int o = l16 + 16 * r;
    if (o < SNO) {
      float vals[8];
      #pragma unroll
      for (int h = 0; h < 8; ++h)
        vals[h] = bf2f(afws[sbase + (size_t)h*(TQ*SNO) + o]);
      float4* dst = (float4*)(af + obase + (size_t)o*SH);
      dst[0] = make_float4(vals[0], vals[1], vals[2], vals[3]);
      dst[1] = make_float4(vals[4], vals[5], vals[6], vals[7]);
    }
  }
}

extern "C" void kernel_launch(void* const* d_in, const int* in_sizes, int n_in,
                              void* d_out, int out_size, void* d_ws, size_t ws_size,
                              hipStream_t stream) {
  const float* q    = (const float*)d_in[0];
  const float* k    = (const float*)d_in[1];
  const float* v    = (const float*)d_in[2];
  const float* Wq   = (const float*)d_in[3];
  const float* bq   = (const float*)d_in[4];
  const float* Wk   = (const float*)d_in[5];
  const float* bk   = (const float*)d_in[6];
  const float* ocpe = (const float*)d_in[7];

  size_t kp_bytes   = (size_t)NROWS * SD * sizeof(float);                  // 16.78 MB
  size_t afws_elems = (size_t)SB * NTILES * SH * (size_t)(TQ * SNO);       // bf16
  size_t need = kp_bytes + afws_elems * 2;

  float* kp = (float*)d_ws;
  unsigned short* afws = (unsigned short*)((char*)d_ws + kp_bytes);

  float* af = (float*)d_out;
  float* op = af + (size_t)SB * SS * SNO * SH;

  proj_kernel<<<NROWS / 64, 256, 0, stream>>>(k, Wk, bk, kp);

  if (ws_size >= need) {
    attn_mfma<true><<<SB * NTILES, 512, 0, stream>>>(q, kp, v, ocpe, Wq, bq, afws, af, op);
    af_transpose<<<SB * NTILES, 512, 0, stream>>>(afws, af);
  } else {
    attn_mfma<false><<<SB * NTILES, 512, 0, stream>>>(q, kp, v, ocpe, Wq, bq, afws, af, op);
  }
}

// Round 3
// 71.974 us; speedup vs baseline: 2.1048x; 1.3133x over previous
//
#include <hip/hip_runtime.h>
#include <cstddef>

#define SB 2
#define SS 4096
#define SH 8
#define SD 64
#define SP 64          // half-window
#define SNO 129        // W+1 offsets
#define TQ 32          // query tokens per attn block
#define NTILES (SS/TQ) // 128
#define AFT (TQ*SNO)   // 4128
#define SSTR 168       // Ss row stride (f16 elems)

typedef _Float16 f16;
typedef __attribute__((ext_vector_type(8))) _Float16 f16x8;
typedef __attribute__((ext_vector_type(4))) float floatx4;

union f16frag { f16 h[8]; ushort4 u4[2]; unsigned int u32[4]; f16x8 v; };

__device__ __forceinline__ float fast_tanh(float x) {
  float ax = fabsf(x);
  float e = __expf(2.0f * ax);
  float t = 1.0f - 2.0f / (e + 1.0f);
  return copysignf(t, x);
}

// read 16 f32 from global, convert, store 16 f16 to LDS
__device__ __forceinline__ void cvt16(const float* __restrict__ src, f16* __restrict__ dst) {
  float4 x0 = *(const float4*)(src);
  float4 x1 = *(const float4*)(src + 4);
  float4 x2 = *(const float4*)(src + 8);
  float4 x3 = *(const float4*)(src + 12);
  f16frag a, c;
  a.h[0]=(f16)x0.x; a.h[1]=(f16)x0.y; a.h[2]=(f16)x0.z; a.h[3]=(f16)x0.w;
  a.h[4]=(f16)x1.x; a.h[5]=(f16)x1.y; a.h[6]=(f16)x1.z; a.h[7]=(f16)x1.w;
  c.h[0]=(f16)x2.x; c.h[1]=(f16)x2.y; c.h[2]=(f16)x2.z; c.h[3]=(f16)x2.w;
  c.h[4]=(f16)x3.x; c.h[5]=(f16)x3.y; c.h[6]=(f16)x3.z; c.h[7]=(f16)x3.w;
  *(ushort4*)(dst)      = a.u4[0];
  *(ushort4*)(dst + 4)  = a.u4[1];
  *(ushort4*)(dst + 8)  = c.u4[0];
  *(ushort4*)(dst + 12) = c.u4[1];
}

// ---------------- prep: project Q,K (f16 MFMA) + convert/transpose V ----------------
// grid: (b,h,chunk64) = 2*8*64 = 1024 blocks x 256
__global__ __launch_bounds__(256) void prep_kernel(
    const float* __restrict__ q, const float* __restrict__ k, const float* __restrict__ v,
    const float* __restrict__ Wq, const float* __restrict__ bq,
    const float* __restrict__ Wk, const float* __restrict__ bk,
    f16* __restrict__ Qf, f16* __restrict__ Kf, f16* __restrict__ Vt)
{
  __shared__ f16 sWq[64*72], sWk[64*72], sQr[64*72], sKr[64*72], sVr[64*72];
  __shared__ float sbq[64], sbk[64];

  int t = threadIdx.x;
  int blk = blockIdx.x;
  int c = blk & 63; int bh = blk >> 6; int h = bh & 7; int b = bh >> 3;
  int s0 = c * 64;

  int dr = t >> 2, e0 = (t & 3) * 16;
  cvt16(Wq + dr*64 + e0, &sWq[dr*72 + e0]);
  cvt16(Wk + dr*64 + e0, &sWk[dr*72 + e0]);
  {
    size_t rbase = ((size_t)(b*SS + s0 + dr)) * (SH*SD) + h*SD + e0;
    cvt16(q + rbase, &sQr[dr*72 + e0]);
    cvt16(k + rbase, &sKr[dr*72 + e0]);
    cvt16(v + rbase, &sVr[dr*72 + e0]);
  }
  if (t < 64) { sbq[t] = bq[t]; sbk[t] = bk[t]; }
  __syncthreads();

  int lane = t & 63, wave = t >> 6;
  int r16 = lane & 15, g = lane >> 4;

  size_t hsbase = (size_t)(b*SH + h) * SS;   // row base in [b,h,s,d]

  #pragma unroll
  for (int j = 0; j < 4; ++j) {
    int tt = wave + 4*j;        // 0..15
    int si = tt >> 2, dj = tt & 3;
    floatx4 accq = {0.f,0.f,0.f,0.f}, acck = {0.f,0.f,0.f,0.f};
    #pragma unroll
    for (int e = 0; e < 64; e += 32) {
      f16x8 aq = *(const f16x8*)&sQr[(si*16 + r16)*72 + e + g*8];
      f16x8 ak = *(const f16x8*)&sKr[(si*16 + r16)*72 + e + g*8];
      f16x8 wq8 = *(const f16x8*)&sWq[(dj*16 + r16)*72 + e + g*8];
      f16x8 wk8 = *(const f16x8*)&sWk[(dj*16 + r16)*72 + e + g*8];
      accq = __builtin_amdgcn_mfma_f32_16x16x32_f16(aq, wq8, accq, 0, 0, 0);
      acck = __builtin_amdgcn_mfma_f32_16x16x32_f16(ak, wk8, acck, 0, 0, 0);
    }
    float biasq = sbq[dj*16 + r16];
    float biask = sbk[dj*16 + r16];
    #pragma unroll
    for (int rr = 0; rr < 4; ++rr) {
      int srow = s0 + si*16 + g*4 + rr;
      Qf[(hsbase + srow)*64 + dj*16 + r16] = (f16)(accq[rr] + biasq);
      Kf[(hsbase + srow)*64 + dj*16 + r16] = (f16)(acck[rr] + biask);
    }
  }

  // V transpose: Vt[b,h,d,s]
  {
    int d = t >> 2, p4 = t & 3, sc0 = p4 * 16;
    f16frag a, c;
    #pragma unroll
    for (int j2 = 0; j2 < 8; ++j2) a.h[j2] = sVr[(sc0 + j2)*72 + d];
    #pragma unroll
    for (int j2 = 0; j2 < 8; ++j2) c.h[j2] = sVr[(sc0 + 8 + j2)*72 + d];
    f16* dst = Vt + ((size_t)(b*SH + h)*64 + d)*SS + s0 + sc0;
    *(ushort4*)dst       = a.u4[0];
    *(ushort4*)(dst + 4) = a.u4[1];
    *(ushort4*)(dst + 8) = c.u4[0];
    *(ushort4*)(dst + 12)= c.u4[1];
  }
}

// ---------------- attention: one block per (b,tile,head) ----------------
// 2048 blocks x 256 threads; LDS ~11.3KB -> 8 blocks/CU
__global__ __launch_bounds__(256, 8) void attn_kernel(
    const f16* __restrict__ Qf, const f16* __restrict__ Kf, const f16* __restrict__ Vt,
    const float* __restrict__ ocpe, f16* __restrict__ afws, float* __restrict__ outp)
{
  __shared__ f16 sSs[TQ*SSTR];
  __shared__ float sOb[SNO];

  int t = threadIdx.x;
  int lane = t & 63, wave = t >> 6;
  int r16 = lane & 15, g = lane >> 4;

  int blk = blockIdx.x;
  int h = blk & 7; int rem = blk >> 3;
  int tile = rem & 127; int b = rem >> 7;
  int t0 = tile * TQ;
  int yg0 = t0 - SP;

  if (t < SNO) sOb[t] = ocpe[t*SH + h];

  // preload Q A-fragments (this wave's i-half)
  int ii = wave & 1;
  const f16* qbase = Qf + ((size_t)(b*SH + h)*SS + t0 + ii*16 + r16)*64;
  f16x8 qa0 = *(const f16x8*)(qbase + g*8);
  f16x8 qa1 = *(const f16x8*)(qbase + 32 + g*8);

  __syncthreads();   // sOb visible

  // scores: 20 tiles (2i x 10y); wave w -> ii=w&1, yy = (w>>1)+2j
  const f16* kbase = Kf + ((size_t)(b*SH + h)*SS)*64;
  #pragma unroll
  for (int j = 0; j < 5; ++j) {
    int yy = (wave >> 1) + 2*j;      // 0..9
    int y = yy*16 + r16;
    int ygr = yg0 + y;
    int ygc = min(max(ygr, 0), SS-1);
    bool yok = (ygr >= 0) & (ygr < SS);
    const f16* kr = kbase + (size_t)ygc * 64;
    f16x8 kb0 = *(const f16x8*)(kr + g*8);
    f16x8 kb1 = *(const f16x8*)(kr + 32 + g*8);
    floatx4 acc = {0.f,0.f,0.f,0.f};
    acc = __builtin_amdgcn_mfma_f32_16x16x32_f16(qa0, kb0, acc, 0, 0, 0);
    acc = __builtin_amdgcn_mfma_f32_16x16x32_f16(qa1, kb1, acc, 0, 0, 0);
    #pragma unroll
    for (int rr = 0; rr < 4; ++rr) {
      int i = ii*16 + g*4 + rr;
      int o = y - i;
      float a = 0.f;
      if (yok && o >= 0 && o <= 2*SP) a = fast_tanh(acc[rr] + sOb[o]);
      sSs[i*SSTR + y] = (f16)a;
    }
  }
  __syncthreads();   // Ss complete

  // PV: wave owns d-chunk d0=wave*16, both i-halves; V garbage at masked y killed by Ss=0
  int d0 = wave * 16;
  const f16* vbase = Vt + ((size_t)(b*SH + h)*64 + d0 + r16)*SS;
  floatx4 acc2[2] = {{0.f,0.f,0.f,0.f},{0.f,0.f,0.f,0.f}};
  #pragma unroll
  for (int ks = 0; ks < 5; ++ks) {
    int yb = ks*32 + g*8;
    int ygr = yg0 + yb;
    int ygc = min(max(ygr, 0), SS-8);
    f16x8 bv = *(const f16x8*)(vbase + ygc);
    f16x8 a0 = *(const f16x8*)&sSs[(r16)*SSTR + yb];
    f16x8 a1 = *(const f16x8*)&sSs[(16 + r16)*SSTR + yb];
    acc2[0] = __builtin_amdgcn_mfma_f32_16x16x32_f16(a0, bv, acc2[0], 0, 0, 0);
    acc2[1] = __builtin_amdgcn_mfma_f32_16x16x32_f16(a1, bv, acc2[1], 0, 0, 0);
  }

  // accumulate out across heads (zeroed via memset each launch)
  #pragma unroll
  for (int pp = 0; pp < 2; ++pp)
    #pragma unroll
    for (int rr = 0; rr < 4; ++rr) {
      int i = pp*16 + g*4 + rr;
      atomicAdd(outp + ((size_t)b*SS + t0 + i)*64 + d0 + r16, acc2[pp][rr]);
    }

  // attn_flat staged slice (contiguous per head)
  {
    int i = t >> 3, l8 = t & 7;
    size_t base = ((size_t)(b*NTILES + tile)*SH + h)*(size_t)AFT + (size_t)i*SNO;
    for (int o = l8; o < SNO; o += 8)
      afws[base + o] = sSs[i*SSTR + i + o];
  }
}

// ---------------- af transpose: ws f16 [b,tile,h,i,o] -> f32 [b,s,o,h] ----------------
__global__ __launch_bounds__(512) void af_transpose(
    const f16* __restrict__ afws, float* __restrict__ af)
{
  __shared__ f16 sAF[4*AFT];   // 33KB, two passes of 4 heads
  int t = threadIdx.x;
  int tile = blockIdx.x & 127; int b = blockIdx.x >> 7;
  int t0 = tile * TQ;
  size_t src = ((size_t)(b*NTILES + tile)*SH) * (size_t)AFT;
  int i = t >> 4, l16 = t & 15;
  size_t obase = ((size_t)b*SS + t0 + i)*(size_t)(SNO*SH);

  #pragma unroll
  for (int half = 0; half < 2; ++half) {
    __syncthreads();
    #pragma unroll
    for (int hh = 0; hh < 4; ++hh) {
      const ushort4* s4 = (const ushort4*)(afws + src + (size_t)(half*4 + hh)*AFT);
      ushort4* dl = (ushort4*)&sAF[hh*AFT];
      for (int idx = t; idx < AFT/4; idx += 512) dl[idx] = s4[idx];
    }
    __syncthreads();
    #pragma unroll
    for (int r = 0; r < 9; ++r) {
      int o = l16 + 16*r;
      if (o < SNO) {
        float4 w;
        w.x = (float)sAF[0*AFT + i*SNO + o];
        w.y = (float)sAF[1*AFT + i*SNO + o];
        w.z = (float)sAF[2*AFT + i*SNO + o];
        w.w = (float)sAF[3*AFT + i*SNO + o];
        *(float4*)(af + obase + (size_t)o*SH + half*4) = w;
      }
    }
  }
}

extern "C" void kernel_launch(void* const* d_in, const int* in_sizes, int n_in,
                              void* d_out, int out_size, void* d_ws, size_t ws_size,
                              hipStream_t stream) {
  const float* q    = (const float*)d_in[0];
  const float* k    = (const float*)d_in[1];
  const float* v    = (const float*)d_in[2];
  const float* Wq   = (const float*)d_in[3];
  const float* bq   = (const float*)d_in[4];
  const float* Wk   = (const float*)d_in[5];
  const float* bk   = (const float*)d_in[6];
  const float* ocpe = (const float*)d_in[7];

  // ws: Kf16 (8.39MB) + Vt (8.39MB) + afws f16 (16.9MB) = 33,685,504 B (== round-2 proven size)
  f16* Kf   = (f16*)d_ws;
  f16* Vt   = Kf + (size_t)SB*SH*SS*SD;
  f16* afws = Vt + (size_t)SB*SH*SS*SD;

  float* af = (float*)d_out;
  float* op = af + (size_t)SB*SS*SNO*SH;
  // Qf16 parks in the af region of d_out (dead until af_transpose overwrites it)
  f16* Qf = (f16*)d_out;

  hipMemsetAsync(op, 0, (size_t)SB*SS*SD*sizeof(float), stream);
  prep_kernel<<<SB*SH*64, 256, 0, stream>>>(q, k, v, Wq, bq, Wk, bk, Qf, Kf, Vt);
  attn_kernel<<<SB*NTILES*SH, 256, 0, stream>>>(Qf, Kf, Vt, ocpe, afws, op);
  af_transpose<<<SB*NTILES, 512, 0, stream>>>(afws, af);
}

// Round 4
// 67.406 us; speedup vs baseline: 2.2474x; 1.0678x over previous
//
#include <hip/hip_runtime.h>
#include <cstddef>

#define SB 2
#define SS 4096
#define SH 8
#define SD 64
#define SP 64          // half-window
#define SNO 129        // W+1 offsets
#define TQ 32          // query tokens per attn block
#define NTILES (SS/TQ) // 128
#define AFT (TQ*SNO)   // 4128
#define SSTR 168       // Ss row stride (f16 elems)

typedef _Float16 f16;
typedef __attribute__((ext_vector_type(8))) _Float16 f16x8;
typedef __attribute__((ext_vector_type(4))) float floatx4;

union f16frag { f16 h[8]; ushort4 u4[2]; unsigned int u32[4]; f16x8 v; };

__device__ __forceinline__ float fast_tanh(float x) {
  float ax = fabsf(x);
  float e = __expf(2.0f * ax);
  float t = 1.0f - 2.0f / (e + 1.0f);
  return copysignf(t, x);
}

// read 16 f32 from global, convert, store 16 f16 to LDS
__device__ __forceinline__ void cvt16(const float* __restrict__ src, f16* __restrict__ dst) {
  float4 x0 = *(const float4*)(src);
  float4 x1 = *(const float4*)(src + 4);
  float4 x2 = *(const float4*)(src + 8);
  float4 x3 = *(const float4*)(src + 12);
  f16frag a, c;
  a.h[0]=(f16)x0.x; a.h[1]=(f16)x0.y; a.h[2]=(f16)x0.z; a.h[3]=(f16)x0.w;
  a.h[4]=(f16)x1.x; a.h[5]=(f16)x1.y; a.h[6]=(f16)x1.z; a.h[7]=(f16)x1.w;
  c.h[0]=(f16)x2.x; c.h[1]=(f16)x2.y; c.h[2]=(f16)x2.z; c.h[3]=(f16)x2.w;
  c.h[4]=(f16)x3.x; c.h[5]=(f16)x3.y; c.h[6]=(f16)x3.z; c.h[7]=(f16)x3.w;
  *(ushort4*)(dst)      = a.u4[0];
  *(ushort4*)(dst + 4)  = a.u4[1];
  *(ushort4*)(dst + 8)  = c.u4[0];
  *(ushort4*)(dst + 12) = c.u4[1];
}

// ---------------- prep: project Q,K (f16 MFMA) + convert/transpose V + zero out ----------------
// grid: (b,h,chunk64) = 2*8*64 = 1024 blocks x 256
__global__ __launch_bounds__(256) void prep_kernel(
    const float* __restrict__ q, const float* __restrict__ k, const float* __restrict__ v,
    const float* __restrict__ Wq, const float* __restrict__ bq,
    const float* __restrict__ Wk, const float* __restrict__ bk,
    f16* __restrict__ Qf, f16* __restrict__ Kf, f16* __restrict__ Vt,
    float* __restrict__ outp)
{
  __shared__ f16 sWq[64*72], sWk[64*72], sQr[64*72], sKr[64*72], sVr[64*72];
  __shared__ float sbq[64], sbk[64];

  int t = threadIdx.x;
  int blk = blockIdx.x;
  int c = blk & 63; int bh = blk >> 6; int h = bh & 7; int b = bh >> 3;
  int s0 = c * 64;

  // zero the out accumulator region (replaces the 40us rocclr fill kernel):
  // 2*4096*64 floats / 1024 blocks = 512 floats per block
  {
    float2 z2 = make_float2(0.f, 0.f);
    *(float2*)(outp + (size_t)blk * 512 + t * 2) = z2;
  }

  int dr = t >> 2, e0 = (t & 3) * 16;
  cvt16(Wq + dr*64 + e0, &sWq[dr*72 + e0]);
  cvt16(Wk + dr*64 + e0, &sWk[dr*72 + e0]);
  {
    size_t rbase = ((size_t)(b*SS + s0 + dr)) * (SH*SD) + h*SD + e0;
    cvt16(q + rbase, &sQr[dr*72 + e0]);
    cvt16(k + rbase, &sKr[dr*72 + e0]);
    cvt16(v + rbase, &sVr[dr*72 + e0]);
  }
  if (t < 64) { sbq[t] = bq[t]; sbk[t] = bk[t]; }
  __syncthreads();

  int lane = t & 63, wave = t >> 6;
  int r16 = lane & 15, g = lane >> 4;

  size_t hsbase = (size_t)(b*SH + h) * SS;   // row base in [b,h,s,d]

  #pragma unroll
  for (int j = 0; j < 4; ++j) {
    int tt = wave + 4*j;        // 0..15
    int si = tt >> 2, dj = tt & 3;
    floatx4 accq = {0.f,0.f,0.f,0.f}, acck = {0.f,0.f,0.f,0.f};
    #pragma unroll
    for (int e = 0; e < 64; e += 32) {
      f16x8 aq = *(const f16x8*)&sQr[(si*16 + r16)*72 + e + g*8];
      f16x8 ak = *(const f16x8*)&sKr[(si*16 + r16)*72 + e + g*8];
      f16x8 wq8 = *(const f16x8*)&sWq[(dj*16 + r16)*72 + e + g*8];
      f16x8 wk8 = *(const f16x8*)&sWk[(dj*16 + r16)*72 + e + g*8];
      accq = __builtin_amdgcn_mfma_f32_16x16x32_f16(aq, wq8, accq, 0, 0, 0);
      acck = __builtin_amdgcn_mfma_f32_16x16x32_f16(ak, wk8, acck, 0, 0, 0);
    }
    float biasq = sbq[dj*16 + r16];
    float biask = sbk[dj*16 + r16];
    #pragma unroll
    for (int rr = 0; rr < 4; ++rr) {
      int srow = s0 + si*16 + g*4 + rr;
      Qf[(hsbase + srow)*64 + dj*16 + r16] = (f16)(accq[rr] + biasq);
      Kf[(hsbase + srow)*64 + dj*16 + r16] = (f16)(acck[rr] + biask);
    }
  }

  // V transpose: Vt[b,h,d,s]
  {
    int d = t >> 2, p4 = t & 3, sc0 = p4 * 16;
    f16frag a, c2;
    #pragma unroll
    for (int j2 = 0; j2 < 8; ++j2) a.h[j2] = sVr[(sc0 + j2)*72 + d];
    #pragma unroll
    for (int j2 = 0; j2 < 8; ++j2) c2.h[j2] = sVr[(sc0 + 8 + j2)*72 + d];
    f16* dst = Vt + ((size_t)(b*SH + h)*64 + d)*SS + s0 + sc0;
    *(ushort4*)dst       = a.u4[0];
    *(ushort4*)(dst + 4) = a.u4[1];
    *(ushort4*)(dst + 8) = c2.u4[0];
    *(ushort4*)(dst + 12)= c2.u4[1];
  }
}

// ---------------- attention: one block per (b,tile,head) ----------------
// 2048 blocks x 256 threads; LDS ~11.3KB -> 8 blocks/CU
__global__ __launch_bounds__(256, 8) void attn_kernel(
    const f16* __restrict__ Qf, const f16* __restrict__ Kf, const f16* __restrict__ Vt,
    const float* __restrict__ ocpe, f16* __restrict__ afws, float* __restrict__ outp)
{
  __shared__ f16 sSs[TQ*SSTR];
  __shared__ float sOb[SNO];

  int t = threadIdx.x;
  int lane = t & 63, wave = t >> 6;
  int r16 = lane & 15, g = lane >> 4;

  int blk = blockIdx.x;
  int h = blk & 7; int rem = blk >> 3;
  int tile = rem & 127; int b = rem >> 7;
  int t0 = tile * TQ;
  int yg0 = t0 - SP;

  if (t < SNO) sOb[t] = ocpe[t*SH + h];

  // preload Q A-fragments (this wave's i-half)
  int ii = wave & 1;
  const f16* qbase = Qf + ((size_t)(b*SH + h)*SS + t0 + ii*16 + r16)*64;
  f16x8 qa0 = *(const f16x8*)(qbase + g*8);
  f16x8 qa1 = *(const f16x8*)(qbase + 32 + g*8);

  __syncthreads();   // sOb visible

  // scores: 20 tiles (2i x 10y); wave w -> ii=w&1, yy = (w>>1)+2j
  const f16* kbase = Kf + ((size_t)(b*SH + h)*SS)*64;
  #pragma unroll
  for (int j = 0; j < 5; ++j) {
    int yy = (wave >> 1) + 2*j;      // 0..9
    int y = yy*16 + r16;
    int ygr = yg0 + y;
    int ygc = min(max(ygr, 0), SS-1);
    bool yok = (ygr >= 0) & (ygr < SS);
    const f16* kr = kbase + (size_t)ygc * 64;
    f16x8 kb0 = *(const f16x8*)(kr + g*8);
    f16x8 kb1 = *(const f16x8*)(kr + 32 + g*8);
    floatx4 acc = {0.f,0.f,0.f,0.f};
    acc = __builtin_amdgcn_mfma_f32_16x16x32_f16(qa0, kb0, acc, 0, 0, 0);
    acc = __builtin_amdgcn_mfma_f32_16x16x32_f16(qa1, kb1, acc, 0, 0, 0);
    #pragma unroll
    for (int rr = 0; rr < 4; ++rr) {
      int i = ii*16 + g*4 + rr;
      int o = y - i;
      float a = 0.f;
      if (yok && o >= 0 && o <= 2*SP) a = fast_tanh(acc[rr] + sOb[o]);
      sSs[i*SSTR + y] = (f16)a;
    }
  }
  __syncthreads();   // Ss complete

  // PV: wave owns d-chunk d0=wave*16, both i-halves; V garbage at masked y killed by Ss=0
  int d0 = wave * 16;
  const f16* vbase = Vt + ((size_t)(b*SH + h)*64 + d0 + r16)*SS;
  floatx4 acc2[2] = {{0.f,0.f,0.f,0.f},{0.f,0.f,0.f,0.f}};
  #pragma unroll
  for (int ks = 0; ks < 5; ++ks) {
    int yb = ks*32 + g*8;
    int ygr = yg0 + yb;
    int ygc = min(max(ygr, 0), SS-8);
    f16x8 bv = *(const f16x8*)(vbase + ygc);
    f16x8 a0 = *(const f16x8*)&sSs[(r16)*SSTR + yb];
    f16x8 a1 = *(const f16x8*)&sSs[(16 + r16)*SSTR + yb];
    acc2[0] = __builtin_amdgcn_mfma_f32_16x16x32_f16(a0, bv, acc2[0], 0, 0, 0);
    acc2[1] = __builtin_amdgcn_mfma_f32_16x16x32_f16(a1, bv, acc2[1], 0, 0, 0);
  }

  // accumulate out across heads (zeroed by prep_kernel earlier in the stream)
  #pragma unroll
  for (int pp = 0; pp < 2; ++pp)
    #pragma unroll
    for (int rr = 0; rr < 4; ++rr) {
      int i = pp*16 + g*4 + rr;
      atomicAdd(outp + ((size_t)b*SS + t0 + i)*64 + d0 + r16, acc2[pp][rr]);
    }

  // attn_flat staged slice (contiguous per head)
  {
    int i = t >> 3, l8 = t & 7;
    size_t base = ((size_t)(b*NTILES + tile)*SH + h)*(size_t)AFT + (size_t)i*SNO;
    for (int o = l8; o < SNO; o += 8)
      afws[base + o] = sSs[i*SSTR + i + o];
  }
}

// ---------------- af transpose: ws f16 [b,tile,h,i,o] -> f32 [b,s,o,h] ----------------
__global__ __launch_bounds__(512) void af_transpose(
    const f16* __restrict__ afws, float* __restrict__ af)
{
  __shared__ f16 sAF[4*AFT];   // 33KB, two passes of 4 heads
  int t = threadIdx.x;
  int tile = blockIdx.x & 127; int b = blockIdx.x >> 7;
  int t0 = tile * TQ;
  size_t src = ((size_t)(b*NTILES + tile)*SH) * (size_t)AFT;
  int i = t >> 4, l16 = t & 15;
  size_t obase = ((size_t)b*SS + t0 + i)*(size_t)(SNO*SH);

  #pragma unroll
  for (int half = 0; half < 2; ++half) {
    __syncthreads();
    #pragma unroll
    for (int hh = 0; hh < 4; ++hh) {
      const ushort4* s4 = (const ushort4*)(afws + src + (size_t)(half*4 + hh)*AFT);
      ushort4* dl = (ushort4*)&sAF[hh*AFT];
      for (int idx = t; idx < AFT/4; idx += 512) dl[idx] = s4[idx];
    }
    __syncthreads();
    #pragma unroll
    for (int r = 0; r < 9; ++r) {
      int o = l16 + 16*r;
      if (o < SNO) {
        float4 w;
        w.x = (float)sAF[0*AFT + i*SNO + o];
        w.y = (float)sAF[1*AFT + i*SNO + o];
        w.z = (float)sAF[2*AFT + i*SNO + o];
        w.w = (float)sAF[3*AFT + i*SNO + o];
        *(float4*)(af + obase + (size_t)o*SH + half*4) = w;
      }
    }
  }
}

extern "C" void kernel_launch(void* const* d_in, const int* in_sizes, int n_in,
                              void* d_out, int out_size, void* d_ws, size_t ws_size,
                              hipStream_t stream) {
  const float* q    = (const float*)d_in[0];
  const float* k    = (const float*)d_in[1];
  const float* v    = (const float*)d_in[2];
  const float* Wq   = (const float*)d_in[3];
  const float* bq   = (const float*)d_in[4];
  const float* Wk   = (const float*)d_in[5];
  const float* bk   = (const float*)d_in[6];
  const float* ocpe = (const float*)d_in[7];

  // ws: Kf16 (8.39MB) + Vt (8.39MB) + afws f16 (16.9MB) = 33,685,504 B (proven fit)
  f16* Kf   = (f16*)d_ws;
  f16* Vt   = Kf + (size_t)SB*SH*SS*SD;
  f16* afws = Vt + (size_t)SB*SH*SS*SD;

  float* af = (float*)d_out;
  float* op = af + (size_t)SB*SS*SNO*SH;
  // Qf16 parks in the af region of d_out (dead until af_transpose overwrites it)
  f16* Qf = (f16*)d_out;

  prep_kernel<<<SB*SH*64, 256, 0, stream>>>(q, k, v, Wq, bq, Wk, bk, Qf, Kf, Vt, op);
  attn_kernel<<<SB*NTILES*SH, 256, 0, stream>>>(Qf, Kf, Vt, ocpe, afws, op);
  af_transpose<<<SB*NTILES, 512, 0, stream>>>(afws, af);
}